// Round 8
// baseline (162.121 us; speedup 1.0000x reference)
//
#include <hip/hip_runtime.h>
#include <hip/hip_bf16.h>

#define HEADS 8
#define HID   64
#define EMB   512
#define HH    512
#define LOCAL 64
#define BS    4
#define NSEQ  2048
#define ROWS  (BS*NSEQ)   // 8192

typedef __attribute__((ext_vector_type(8))) short short8;   // 8 bf16 = 4 VGPRs
typedef __attribute__((ext_vector_type(4))) float f32x4;

__device__ __forceinline__ ushort f2b(float f) {
    union { float f; unsigned u; } c; c.f = f;
    return (ushort)((c.u + 0x7FFFu + ((c.u >> 16) & 1u)) >> 16);
}
__device__ __forceinline__ float b2f(ushort u) {
    union { unsigned u; float f; } c; c.u = ((unsigned)u) << 16; return c.f;
}

__device__ __forceinline__ void async16(const void* g, void* l) {
    __builtin_amdgcn_global_load_lds(
        (const __attribute__((address_space(1))) void*)g,
        (__attribute__((address_space(3))) void*)l, 16, 0, 0);
}

// ---------------------------------------------------------------------------
// prep: blocks [0,4096) convert x -> bf16; blocks [4096,8192) transpose the
// four weight matrices to n-major bf16.
// ---------------------------------------------------------------------------
__global__ __launch_bounds__(256) void prep(
    const float* __restrict__ x,
    const float* __restrict__ w0, const float* __restrict__ w1,
    const float* __restrict__ w2, const float* __restrict__ w3,
    ushort* __restrict__ xb, ushort* __restrict__ dst012,
    ushort* __restrict__ dst3)
{
    __shared__ float s[16][17];
    const int id = blockIdx.x;
    if (id < 4096) {               // x convert: 4096*256 float4 = 8192*512
        const int i = id * 256 + threadIdx.x;
        float4 f = ((const float4*)x)[i];
        ushort4 u;
        u.x = f2b(f.x); u.y = f2b(f.y); u.z = f2b(f.z); u.w = f2b(f.w);
        ((ushort4*)xb)[i] = u;
    } else {                       // weight transpose
        const int id2 = id - 4096;
        const int z = id2 >> 10, t = id2 & 1023;
        const float* src = (z == 0) ? w0 : (z == 1) ? w1 : (z == 2) ? w2 : w3;
        ushort* dst = (z < 3) ? dst012 + (size_t)z * 512 * 512 : dst3;
        const int n0 = (t & 31) * 16, k0 = (t >> 5) * 16;
        const int tx = threadIdx.x & 15, ty = threadIdx.x >> 4;
        s[ty][tx] = src[(size_t)(k0 + ty) * 512 + n0 + tx];
        __syncthreads();
        dst[(size_t)(n0 + ty) * 512 + k0 + tx] = f2b(s[tx][ty]);
    }
}

// v[b*2048+n][h*64+d] -> vT[((b*8+h)*64+d)*2048 + n]; 64x64 tiles via LDS.
__global__ __launch_bounds__(256) void transpose_v(
    const ushort* __restrict__ v, ushort* __restrict__ vT)
{
    __shared__ ushort s[64][65];
    const int nt = blockIdx.x, h = blockIdx.y, b = blockIdx.z;
    const int tid = threadIdx.x;
    {
        const int n = tid >> 2, d0 = (tid & 3) * 16;
        const ushort* g = v + ((size_t)(b * NSEQ + nt * 64 + n)) * HH + h * HID + d0;
        *(short8*)&s[n][d0]     = *(const short8*)g;
        *(short8*)&s[n][d0 + 8] = *(const short8*)(g + 8);
    }
    __syncthreads();
    {
        const int d = tid & 63, seg = tid >> 6;
        ushort* gout = vT + ((size_t)((b * HEADS + h) * HID + d)) * NSEQ + nt * 64 + seg * 16;
#pragma unroll
        for (int j = 0; j < 16; ++j) gout[j] = s[seg * 16 + j][d];
    }
}

// ---------------------------------------------------------------------------
// MFMA GEMM (m97-style staging).  1-D grid, lin = col*64 + row -> A-stripe
// sharers co-XCD.  Epilogue repacks C through LDS for 16B vector stores.
// MODE 0: -> q/k/v bf16 (q,k scaled 0.125).  MODE 1: +bias -> fp32 out.
// ---------------------------------------------------------------------------
template <int MODE>
__global__ __launch_bounds__(256) void gemm_mfma(
    const ushort* __restrict__ A, const ushort* __restrict__ Bt,
    ushort* __restrict__ oq, ushort* __restrict__ ok, ushort* __restrict__ ov,
    const float* __restrict__ bias, float* __restrict__ out)
{
    __shared__ ushort Sbuf[2 * 128 * 32];   // As | Bs; reused by epilogue
    ushort* As = Sbuf;
    ushort* Bs = Sbuf + 128 * 32;
    const int tid  = threadIdx.x;
    const int rowB = (blockIdx.x & 63) * 128;
    const int colB = (blockIdx.x >> 6) * 128;
    const int wave = tid >> 6, lane = tid & 63;
    const int wm = wave & 1, wn = wave >> 1;
    const int l15 = lane & 15, quad = lane >> 4;

    f32x4 acc[4][4] = {};

    for (int kt = 0; kt < 512; kt += 32) {
#pragma unroll
        for (int p = 0; p < 2; ++p) {
            const int c = p * 256 + tid;
            const int row = c >> 2, sc = (c & 3) * 8;
            async16(A  + (size_t)(rowB + row) * 512 + kt + sc, &As[c * 8]);
            async16(Bt + (size_t)(colB + row) * 512 + kt + sc, &Bs[c * 8]);
        }
        __syncthreads();

        short8 af[4], bf[4];
#pragma unroll
        for (int mi = 0; mi < 4; ++mi)
            af[mi] = *(const short8*)&As[(wm * 64 + mi * 16 + l15) * 32 + quad * 8];
#pragma unroll
        for (int ni = 0; ni < 4; ++ni)
            bf[ni] = *(const short8*)&Bs[(wn * 64 + ni * 16 + l15) * 32 + quad * 8];
#pragma unroll
        for (int mi = 0; mi < 4; ++mi)
#pragma unroll
            for (int ni = 0; ni < 4; ++ni)
                acc[mi][ni] = __builtin_amdgcn_mfma_f32_16x16x32_bf16(
                    af[mi], bf[ni], acc[mi][ni], 0, 0, 0);
        __syncthreads();
    }
    // All waves past final barrier: Sbuf is dead -> per-wave repack regions.

    if (MODE == 0) {
        ushort* T = Sbuf + wave * 2048;      // 16 rows x stride 72 (1152 used)
        const int sec = colB >> 9;           // block-uniform
        ushort* dst = (sec == 0) ? oq : (sec == 1) ? ok : ov;
        const float s = (sec == 2) ? 1.0f : 0.125f;
        const int cb = (colB & 511) + wn * 64;
#pragma unroll
        for (int mi = 0; mi < 4; ++mi) {
#pragma unroll
            for (int ni = 0; ni < 4; ++ni)
#pragma unroll
                for (int r = 0; r < 4; ++r)
                    T[(quad * 4 + r) * 72 + ni * 16 + l15] = f2b(acc[mi][ni][r] * s);
#pragma unroll
            for (int u = 0; u < 2; ++u) {    // 128 chunks: 16 rows x 8 ushort8
                const int cid = lane * 2 + u;
                const int row = cid >> 3, ch = cid & 7;
                const int grow = rowB + wm * 64 + mi * 16 + row;
                *(short8*)&dst[(size_t)grow * HH + cb + ch * 8] =
                    *(const short8*)&T[row * 72 + ch * 8];
            }
        }
    } else {
        float* Tf = (float*)Sbuf + wave * 1024;   // 16 rows x 64 fp32 (4 KB)
        float bcol[4];
#pragma unroll
        for (int ni = 0; ni < 4; ++ni)
            bcol[ni] = bias[colB + wn * 64 + ni * 16 + l15];
#pragma unroll
        for (int mi = 0; mi < 4; ++mi) {
#pragma unroll
            for (int ni = 0; ni < 4; ++ni)
#pragma unroll
                for (int r = 0; r < 4; ++r)
                    Tf[(quad * 4 + r) * 64 + ni * 16 + l15] = acc[mi][ni][r] + bcol[ni];
#pragma unroll
            for (int u = 0; u < 4; ++u) {    // 256 chunks: 16 rows x 16 float4
                const int cid = lane * 4 + u;
                const int row = cid >> 4, ch = cid & 15;
                const int grow = rowB + wm * 64 + mi * 16 + row;
                *(float4*)&out[(size_t)grow * EMB + colB + wn * 64 + ch * 4] =
                    *(const float4*)&Tf[row * 64 + ch * 4];
            }
        }
    }
}

// ---------------------------------------------------------------------------
// Attention: ONE 64-thread block per 16 queries (barrier-free wave), grid
// 4096.  lin = qidx*32 + (h + 8b): same-slice blocks share lin%8 -> same XCD.
// qidx reversed so heavy query blocks dispatch first.
// ---------------------------------------------------------------------------
struct __align__(16) WaveWS {
    union { ushort Ps[16][112]; float Ot[16][66]; } u;  // 4224 B
    float ps_str[32][17];                               // 2176 B
    float rden[16];                                     // 64 B
};

__global__ __launch_bounds__(64) void attn_v3(
    const ushort* __restrict__ q, const ushort* __restrict__ k,
    const ushort* __restrict__ v, const ushort* __restrict__ vT,
    ushort* __restrict__ o)
{
    const int slice = blockIdx.x & 31;           // h + 8*b
    const int qidx  = 127 - (int)(blockIdx.x >> 5);   // 16-query tile, heavy 1st
    const int h = slice & 7, b = slice >> 3;
    const int lane = threadIdx.x;
    const int l15 = lane & 15, quad = lane >> 4;
    const int qw = qidx * 16;
    const int qb = qw >> 6;
    const int nstr = (qb >= 2) ? (qb - 1) : 0;   // strided j = 2..qb
    const int band0 = qw - 64;

    __shared__ WaveWS S;

    const ptrdiff_t rowb = (ptrdiff_t)b * NSEQ;
    const int hb = h * HID;

    // zero Ps pad columns [80,96)
    { ushort4 z = {0, 0, 0, 0}; *(ushort4*)&S.u.Ps[l15][80 + quad * 4] = z; }

    // Q A-fragments direct from global
    short8 afq[2];
    {
        const ushort* qp = q + (rowb + qw + l15) * 512 + hb + quad * 8;
        afq[0] = *(const short8*)qp;
        afq[1] = *(const short8*)(qp + 32);
    }

    // ---- local band QK^T: 5 key tiles ----
    f32x4 accL[5];
#pragma unroll
    for (int kt = 0; kt < 5; ++kt) {
        accL[kt] = (f32x4){0.f, 0.f, 0.f, 0.f};
        const ushort* kp = k + (rowb + band0 + kt * 16 + l15) * 512 + hb + quad * 8;
        const short8 b0 = *(const short8*)kp;
        const short8 b1 = *(const short8*)(kp + 32);
        accL[kt] = __builtin_amdgcn_mfma_f32_16x16x32_bf16(afq[0], b0, accL[kt], 0, 0, 0);
        accL[kt] = __builtin_amdgcn_mfma_f32_16x16x32_bf16(afq[1], b1, accL[kt], 0, 0, 0);
    }

    // ---- strided scores: 8 key tiles per MFMA pass, keep diagonals ----
    const bool isdiag = ((l15 >> 2) == quad);
    const int rr = l15 & 3;
    for (int p = 0; p * 8 < nstr; ++p) {
        f32x4 accS[8];
#pragma unroll
        for (int t = 0; t < 8; ++t) {
            accS[t] = (f32x4){0.f, 0.f, 0.f, 0.f};
            const int jj = p * 8 + t;
            const ushort* kp = k + (rowb + (qw - 64 * (jj + 2)) + l15) * 512 + hb + quad * 8;
            const short8 b0 = *(const short8*)kp;   // garbage if jj>=nstr (finite, discarded)
            const short8 b1 = *(const short8*)(kp + 32);
            accS[t] = __builtin_amdgcn_mfma_f32_16x16x32_bf16(afq[0], b0, accS[t], 0, 0, 0);
            accS[t] = __builtin_amdgcn_mfma_f32_16x16x32_bf16(afq[1], b1, accS[t], 0, 0, 0);
        }
        if (isdiag) {
#pragma unroll
            for (int t = 0; t < 8; ++t) {
                const int jj = p * 8 + t;
                const float val = (rr == 0) ? accS[t][0] : (rr == 1) ? accS[t][1]
                                : (rr == 2) ? accS[t][2] : accS[t][3];
                if (jj < nstr) S.ps_str[jj][l15] = val;
            }
        }
    }

    // ---- masked softmax (C-layout rows), P -> LDS bf16 ----
    float rden_r[4];
#pragma unroll
    for (int r = 0; r < 4; ++r) {
        const int row16 = quad * 4 + r;
        float pm[5], mx = -1e30f;
#pragma unroll
        for (int kt = 0; kt < 5; ++kt) {
            const int col = kt * 16 + l15;
            const bool okm = (col >= row16) && (col <= 64 + row16) && (band0 + col >= 0);
            pm[kt] = okm ? accL[kt][r] : -1e30f;
            mx = fmaxf(mx, pm[kt]);
        }
        const float rs0 = (l15 < nstr)      ? S.ps_str[l15][row16]      : -1e30f;
        const float rs1 = (l15 + 16 < nstr) ? S.ps_str[l15 + 16][row16] : -1e30f;
        mx = fmaxf(mx, fmaxf(rs0, rs1));
        mx = fmaxf(mx, __shfl_xor(mx, 1)); mx = fmaxf(mx, __shfl_xor(mx, 2));
        mx = fmaxf(mx, __shfl_xor(mx, 4)); mx = fmaxf(mx, __shfl_xor(mx, 8));
        float sum = 0.f;
#pragma unroll
        for (int kt = 0; kt < 5; ++kt) {
            const float pv = __expf(pm[kt] - mx);
            sum += pv;
            S.u.Ps[row16][kt * 16 + l15] = f2b(pv);
        }
        if (l15 < nstr)      { const float e = __expf(rs0 - mx); S.ps_str[l15][row16] = e;      sum += e; }
        if (l15 + 16 < nstr) { const float e = __expf(rs1 - mx); S.ps_str[l15 + 16][row16] = e; sum += e; }
        sum += __shfl_xor(sum, 1); sum += __shfl_xor(sum, 2);
        sum += __shfl_xor(sum, 4); sum += __shfl_xor(sum, 8);
        rden_r[r] = 1.0f / sum;
        if (l15 == 0) S.rden[row16] = rden_r[r];
    }

    // ---- PV local via MFMA: A = Ps (bf16), B = vT rows (global, contig) ----
    f32x4 O[4];
#pragma unroll
    for (int nt = 0; nt < 4; ++nt) O[nt] = (f32x4){0.f, 0.f, 0.f, 0.f};
    const ushort* vtb = vT + ((ptrdiff_t)(b * HEADS + h) * HID) * NSEQ;
#pragma unroll
    for (int ks = 0; ks < 3; ++ks) {
        const short8 ap = *(const short8*)&S.u.Ps[l15][ks * 32 + quad * 8];
#pragma unroll
        for (int nt = 0; nt < 4; ++nt) {
            const short8 bp = *(const short8*)(
                vtb + (ptrdiff_t)(nt * 16 + l15) * NSEQ + band0 + ks * 32 + quad * 8);
            O[nt] = __builtin_amdgcn_mfma_f32_16x16x32_bf16(ap, bp, O[nt], 0, 0, 0);
        }
    }

    // ---- strided PV: lane = d, p broadcast from LDS ----
    float O2[16];
#pragma unroll
    for (int i2 = 0; i2 < 16; ++i2) O2[i2] = 0.f;
    for (int jj = 0; jj < nstr; ++jj) {
        const ptrdiff_t base = qw - 64 * (jj + 2);
#pragma unroll
        for (int i2 = 0; i2 < 16; ++i2) {
            const float p = S.ps_str[jj][i2];
            O2[i2] += p * b2f(v[(rowb + base + i2) * 512 + hb + lane]);
        }
    }

    // ---- merge (C-layout + lane=d) via LDS, store bf16 ----
#pragma unroll
    for (int nt = 0; nt < 4; ++nt)
#pragma unroll
        for (int r = 0; r < 4; ++r)
            S.u.Ot[quad * 4 + r][nt * 16 + l15] = O[nt][r] * rden_r[r];
#pragma unroll
    for (int i2 = 0; i2 < 16; ++i2) {
        const float val = S.u.Ot[i2][lane] + O2[i2] * S.rden[i2];
        o[(rowb + qw + i2) * 512 + hb + lane] = f2b(val);
    }
}

// ---------------------------------------------------------------------------
extern "C" void kernel_launch(void* const* d_in, const int* in_sizes, int n_in,
                              void* d_out, int out_size, void* d_ws, size_t ws_size,
                              hipStream_t stream)
{
    // dict order: x, w_keys, w_queries, w_values, w_unify, b_unify (fp32)
    const float* x  = (const float*)d_in[0];
    const float* wk = (const float*)d_in[1];
    const float* wq = (const float*)d_in[2];
    const float* wv = (const float*)d_in[3];
    const float* wu = (const float*)d_in[4];
    const float* bu = (const float*)d_in[5];
    float* out = (float*)d_out;

    // ws (bf16): xb 8M | wbt 1.5M | wubt .5M | ob 8M | qb 8M | kb 8M | vT 8M | vb 8M
    ushort* xb   = (ushort*)d_ws;
    ushort* wbt  = xb   + (size_t)ROWS * EMB;
    ushort* wubt = wbt  + (size_t)1536 * 512;
    ushort* ob   = wubt + (size_t)512 * 512;
    ushort* qbuf = ob   + (size_t)ROWS * HH;
    ushort* kbuf = qbuf + (size_t)ROWS * HH;
    ushort* vTb  = kbuf + (size_t)ROWS * HH;
    ushort* vbuf = vTb  + (size_t)ROWS * HH;

    prep<<<8192, 256, 0, stream>>>(x, wq, wk, wv, wu, xb, wbt, wubt);
    gemm_mfma<0><<<12 * 64, 256, 0, stream>>>(xb, wbt, qbuf, kbuf, vbuf,
                                              nullptr, nullptr);
    transpose_v<<<dim3(NSEQ / 64, HEADS, BS), 256, 0, stream>>>(vbuf, vTb);
    attn_v3<<<128 * 32, 64, 0, stream>>>(qbuf, kbuf, vbuf, vTb, ob);
    gemm_mfma<1><<<4 * 64, 256, 0, stream>>>(ob, wubt, nullptr, nullptr, nullptr,
                                             bu, out);
}